// Round 9
// baseline (8751.883 us; speedup 1.0000x reference)
//
#include <hip/hip_runtime.h>
#include <hip/hip_bf16.h>

// Problem: B=64, S=512, D=1024, gates N=4096, K=2048 (x ++ h)
// W columns PERMUTED: col' = 4*o + g  (o = output dim 0..1023, g = gate 0..3)
// so each 32-col' tile = complete gate quads for 8 outputs -> phase 2 is WG-local.

typedef __attribute__((ext_vector_type(8))) short bf16x8;
typedef __attribute__((ext_vector_type(16))) float f32x16;

#define AT_RLX __ATOMIC_RELAXED
#define SC_AGT __HIP_MEMORY_SCOPE_AGENT

// ---------- prep kernels ----------

// Wt[col'*2048 + k] = bf16(W[k*4096 + n]),  col' = ((n&1023)<<2) | (n>>10)
__global__ __launch_bounds__(256) void conv_w(const float* __restrict__ W,
                                              __hip_bfloat16* __restrict__ Wt) {
    size_t id = (size_t)blockIdx.x * 256 + threadIdx.x;   // < 2048*4096
    int k = (int)(id >> 12);
    int n = (int)(id & 4095);
    int cp = ((n & 1023) << 2) | (n >> 10);
    Wt[(size_t)cp * 2048 + k] = __float2bfloat16(W[id]);
}

// Xt[(s*64+b)*1024 + d] = bf16(X[(b*512+s)*1024 + d])
__global__ __launch_bounds__(256) void conv_x(const float* __restrict__ X,
                                              __hip_bfloat16* __restrict__ Xt) {
    size_t id = (size_t)blockIdx.x * 256 + threadIdx.x;   // < 64*512*1024
    int d   = (int)(id & 1023);
    int row = (int)(id >> 10);
    int s = row >> 6;
    int b = row & 63;
    Xt[id] = __float2bfloat16(X[(((size_t)b * 512 + s) << 10) + d]);
}

// h init broadcast; zero hflag[1024], sflag[1024] (u32, 16B stride) and stats[4096] f32.
__global__ __launch_bounds__(256) void init_h(const float* __restrict__ hx,
                                              __hip_bfloat16* __restrict__ h,
                                              unsigned int* __restrict__ hflag,
                                              unsigned int* __restrict__ sflag,
                                              float* __restrict__ stats) {
    int id = blockIdx.x * 256 + threadIdx.x;              // < 65536
    h[id] = __float2bfloat16(hx[id & 1023]);
    if (id < 1024) hflag[id] = 0u;
    else if (id < 2048) sflag[id - 1024] = 0u;
    else if (id < 6144) stats[id - 2048] = 0.0f;
}

// ---------- coherence-point primitives (proven r5-r8) ----------
__device__ __forceinline__ bf16x8 ld_coh16(const short* p) {
    union { unsigned long long u[2]; bf16x8 v; } r;
    r.u[0] = __hip_atomic_load((const unsigned long long*)p,     AT_RLX, SC_AGT);
    r.u[1] = __hip_atomic_load((const unsigned long long*)p + 1, AT_RLX, SC_AGT);
    return r.v;
}
__device__ __forceinline__ float2 ld_coh8f(const float* p) {
    union { unsigned long long u; float2 f; } c;
    c.u = __hip_atomic_load((const unsigned long long*)p, AT_RLX, SC_AGT);
    return c.f;
}
// 4B write EXECUTED AT the IF coherence point (returning exchange; r5 lesson)
__device__ __forceinline__ void xchg4(unsigned int* p, unsigned int v) {
    unsigned int old = __hip_atomic_exchange(p, v, AT_RLX, SC_AGT);
    asm volatile("" :: "v"(old));
}

// ---------- fused persistent recurrence: producer-owns-phase-2 ----------
// 256 WGs x 256 thr. WG b: nt=b>>1 (8 outputs o in [8nt,8nt+8)), mt=b&1 (rows mt*32..+32).
// Per step:
//  phase 1: waves kc<2 x-part MFMAs; kc>=2 poll hflag (64 producers of their o-half),
//           h-part MFMAs via IF loads. LDS-combine 4 K-chunks (padded 33-stride).
//  phase 2 (ALL WGs, local): per-thread (row=t>>3, oi=t&7) gate quad from LDS + bias;
//           row-stats shuffle-reduce -> 2 atomic f32 adds into stats[s&3][mt][row] (64B/row);
//           sflag[wg]=s+1; poll 128 sflags of own mt; read stats; LN+gates+c;
//           h packed xchg4 -> hflag[wg]=s+1 -> out stores.
// Stats buffer 4-deep rotation; buf (s+3)&3 reset by WGs b<2 at step s (safe: h(s-1)
// complete ==> all stats(s-1) reads done, since every WG reads stats before writing h).
// Single h buffer safe: stats(s) ready ==> all h(s-1) reads finished (adds follow the
// post-MFMA barrier).
__global__ __launch_bounds__(256, 1) void lstm_fused(
    const __hip_bfloat16* __restrict__ Xt,
    const __hip_bfloat16* __restrict__ Wt,
    __hip_bfloat16* __restrict__ h,
    const float* __restrict__ bias,
    const float* __restrict__ lnw,
    const float* __restrict__ lnb,
    const float* __restrict__ cx,
    float* __restrict__ out,
    unsigned int* __restrict__ hflag,   // [256 wg]*4 stride (16B)
    unsigned int* __restrict__ sflag,   // [256 wg]*4 stride (16B)
    float* __restrict__ stats)          // [4][2][32][16]  (64B per row)
{
    const int tid  = threadIdx.x;
    const int lane = tid & 63;
    const int wv   = tid >> 6;          // wave: 0..3
    const int b    = blockIdx.x;        // 0..255

    const int nt = b >> 1;              // output group: o in [8nt, 8nt+8)
    const int mt = b & 1;               // row block
    const int kc = wv;                  // K chunk (512 each); 0,1 = x; 2,3 = h
    const int cl = lane & 31;
    const int kh = (lane >> 5) * 8;
    const int n0 = nt * 32;             // col' base

    __shared__ float lds_f[4224];       // 4 x 32 x 33 (pad: conflict-free)

    // ---- B chunk in registers (once) ----
    const short* bp = (const short*)Wt + (size_t)(n0 + cl) * 2048 + kc * 512 + kh;
    bf16x8 breg[32];
#pragma unroll
    for (int i = 0; i < 32; ++i) breg[i] = *(const bf16x8*)(bp + i * 16);

    // ---- A pointers ----
    const short* xbase = (const short*)Xt + (size_t)(mt * 32 + cl) * 1024 + kc * 512 + kh;
    const short* hrow  = (const short*)h  + (size_t)(mt * 32 + cl) * 1024 + (kc - 2) * 512 + kh;
    const int hfi = mt * 128 + (kc >= 2 ? 64 * (kc - 2) : 0) + lane;  // poll target

    // ---- phase-2 per-thread constants ----
    const int row = tid >> 3;           // 0..31 (local row)
    const int oi  = tid & 7;
    const int o   = 8 * nt + oi;        // output dim 0..1023
    const int gr  = mt * 32 + row;      // global batch row
    float bias_r[4], lnw_r[4], lnb_r[4];
#pragma unroll
    for (int g = 0; g < 4; ++g) {
        int col = g * 1024 + o;
        bias_r[g] = bias[col];
        lnw_r[g]  = lnw[col];
        lnb_r[g]  = lnb[col];
    }
    float cr = cx[o];

    for (int s = 0; s < 512; ++s) {
        // ================= phase 1: GEMM =================
        f32x16 accA, accB;
#pragma unroll
        for (int i = 0; i < 16; ++i) { accA[i] = 0.f; accB[i] = 0.f; }
        if (kc < 2) {
            const short* ap = xbase + (size_t)s * 65536;
#pragma unroll
            for (int i = 0; i < 16; ++i) {
                bf16x8 a0 = *(const bf16x8*)(ap + i * 16);
                bf16x8 a1 = *(const bf16x8*)(ap + (i + 16) * 16);
                accA = __builtin_amdgcn_mfma_f32_32x32x16_bf16(a0, breg[i],      accA, 0, 0, 0);
                accB = __builtin_amdgcn_mfma_f32_32x32x16_bf16(a1, breg[i + 16], accB, 0, 0, 0);
            }
        } else {
            for (;;) {  // wait h(s-1) from the 64 producers of this o-half (1 flag/lane)
                unsigned int f = __hip_atomic_load(&hflag[hfi * 4], AT_RLX, SC_AGT);
                if (__all((int)(f >= (unsigned int)s))) break;
                __builtin_amdgcn_s_sleep(1);
            }
            asm volatile("" ::: "memory");
#pragma unroll
            for (int i = 0; i < 16; ++i) {
                bf16x8 a0 = ld_coh16(hrow + i * 16);
                bf16x8 a1 = ld_coh16(hrow + (i + 16) * 16);
                accA = __builtin_amdgcn_mfma_f32_32x32x16_bf16(a0, breg[i],      accA, 0, 0, 0);
                accB = __builtin_amdgcn_mfma_f32_32x32x16_bf16(a1, breg[i + 16], accB, 0, 0, 0);
            }
        }
#pragma unroll
        for (int r = 0; r < 16; ++r) {
            int rl = (r & 3) + 8 * (r >> 2) + 4 * (lane >> 5);
            lds_f[kc * 1056 + rl * 33 + cl] = accA[r] + accB[r];
        }
        __syncthreads();

        // rotate-reset stats buffer (WGs b<2 only; ordered via flag chain)
        if (b < 2 && tid < 64)
            __hip_atomic_store(&stats[((s + 3) & 3) * 1024 + b * 512 +
                                      (tid >> 1) * 16 + (tid & 1)], 0.0f, AT_RLX, SC_AGT);

        // ================= phase 2 (WG-local) =================
        float v[4];
        float s1 = 0.f, s2 = 0.f;
#pragma unroll
        for (int g = 0; g < 4; ++g) {
            int e = row * 33 + 4 * oi + g;
            float x = lds_f[e] + lds_f[1056 + e] + lds_f[2112 + e] + lds_f[3168 + e]
                    + bias_r[g];
            v[g] = x;
            s1 += x;
            s2 += x * x;
        }
        // reduce over the 8 threads of this row (lanes differ in oi bits only)
        s1 += __shfl_xor(s1, 1);  s2 += __shfl_xor(s2, 1);
        s1 += __shfl_xor(s1, 2);  s2 += __shfl_xor(s2, 2);
        s1 += __shfl_xor(s1, 4);  s2 += __shfl_xor(s2, 4);
        if (oi == 0) {
            float* sb = &stats[(s & 3) * 1024 + mt * 512 + row * 16];
            __hip_atomic_fetch_add(sb,     s1, AT_RLX, SC_AGT);
            __hip_atomic_fetch_add(sb + 1, s2, AT_RLX, SC_AGT);
        }
        __syncthreads();   // vmcnt drain: adds executed at IF
        if (tid == 0)
            __hip_atomic_store(&sflag[(mt * 128 + nt) * 4], (unsigned int)(s + 1),
                               AT_RLX, SC_AGT);
        if (tid < 128) {   // wait all 128 producers of my mt-block's stats
            const unsigned int* f = &sflag[(mt * 128 + tid) * 4];
            while (__hip_atomic_load(f, AT_RLX, SC_AGT) < (unsigned int)(s + 1))
                __builtin_amdgcn_s_sleep(1);
        }
        __syncthreads();
        asm volatile("" ::: "memory");

        float2 st = ld_coh8f(&stats[(s & 3) * 1024 + mt * 512 + row * 16]);
        float mean = st.x * (1.f / 4096.f);
        float var  = st.y * (1.f / 4096.f) - mean * mean;
        float rstd = rsqrtf(var + 1e-5f);

        float yi = (v[0] - mean) * rstd * lnw_r[0] + lnb_r[0];
        float yf = (v[1] - mean) * rstd * lnw_r[1] + lnb_r[1];
        float yo = (v[2] - mean) * rstd * lnw_r[2] + lnb_r[2];
        float yh = (v[3] - mean) * rstd * lnw_r[3] + lnb_r[3];
        float ig = 1.f / (1.f + __expf(-yi));
        float fg = 1.f / (1.f + __expf(-yf));
        float og = 1.f / (1.f + __expf(-yo));
        float hd = tanhf(yh);
        float cn = fg * cr + ig * hd;
        cr = cn;
        float hn = og * tanhf(cn);

        // h handoff FIRST (packed pair xchg by even-oi threads), then flag, then out
        float hp = __shfl_down(hn, 1);
        if ((oi & 1) == 0) {
            unsigned int lo = __builtin_bit_cast(unsigned short, __float2bfloat16(hn));
            unsigned int hi = __builtin_bit_cast(unsigned short, __float2bfloat16(hp));
            xchg4((unsigned int*)((unsigned short*)h + gr * 1024 + o), lo | (hi << 16));
        }
        __syncthreads();   // vmcnt drain: h(s) at coherence point
        if (tid == 0)
            __hip_atomic_store(&hflag[(mt * 128 + nt) * 4], (unsigned int)(s + 1),
                               AT_RLX, SC_AGT);
        out[(size_t)gr * 524288 + (size_t)s * 1024 + o] = hn;
    }
}

// ---------- launcher ----------
extern "C" void kernel_launch(void* const* d_in, const int* in_sizes, int n_in,
                              void* d_out, int out_size, void* d_ws, size_t ws_size,
                              hipStream_t stream) {
    const float* X   = (const float*)d_in[0];   // [64,512,1024]
    const float* W   = (const float*)d_in[1];   // [2048,4096]
    const float* bv  = (const float*)d_in[2];   // [4096]
    const float* lnw = (const float*)d_in[3];   // [4096]
    const float* lnb = (const float*)d_in[4];   // [4096]
    const float* hx  = (const float*)d_in[5];   // [1,1024]
    const float* cx  = (const float*)d_in[6];   // [1,1024]
    float* out = (float*)d_out;                 // [64,512,1024]

    char* base = (char*)d_ws;
    __hip_bfloat16* Wt    = (__hip_bfloat16*)(base);                 // 16 MB
    __hip_bfloat16* Xt    = (__hip_bfloat16*)(base + 16777216);      // 64 MB
    __hip_bfloat16* hbuf  = (__hip_bfloat16*)(base + 83886080);      // 128 KB
    unsigned int*   hflag = (unsigned int*)  (base + 84017152);      // 4 KB
    unsigned int*   sflag = (unsigned int*)  (base + 84021248);      // 4 KB
    float*          stats = (float*)         (base + 84025344);      // 16 KB
    // total ~84.04 MB

    conv_w<<<32768, 256, 0, stream>>>(W, Wt);
    conv_x<<<131072, 256, 0, stream>>>(X, Xt);
    init_h<<<256, 256, 0, stream>>>(hx, hbuf, hflag, sflag, stats);

    lstm_fused<<<256, 256, 0, stream>>>(Xt, Wt, hbuf, bv, lnw, lnb, cx, out,
                                        hflag, sflag, stats);
}

// Round 10
// 5548.603 us; speedup vs baseline: 1.5773x; 1.5773x over previous
//
#include <hip/hip_runtime.h>
#include <hip/hip_bf16.h>

// Problem: B=64, S=512, D=1024, gates N=4096, K=2048 (x ++ h)

typedef __attribute__((ext_vector_type(8))) short bf16x8;
typedef __attribute__((ext_vector_type(16))) float f32x16;
typedef __attribute__((ext_vector_type(4)))  int   i32x4;
typedef __attribute__((ext_vector_type(4)))  float f32x4;

#define AT_RLX __ATOMIC_RELAXED
#define SC_AGT __HIP_MEMORY_SCOPE_AGENT

// ---------- prep kernels ----------

// Wt[n*2048 + k] = bf16(W[k*4096 + n])   (B^T layout: 8 consecutive k per lane)
__global__ __launch_bounds__(256) void conv_w(const float* __restrict__ W,
                                              __hip_bfloat16* __restrict__ Wt) {
    size_t id = (size_t)blockIdx.x * 256 + threadIdx.x;   // < 2048*4096
    int k = (int)(id >> 12);
    int n = (int)(id & 4095);
    Wt[(size_t)n * 2048 + k] = __float2bfloat16(W[id]);
}

// Xt[(s*64+b)*1024 + d] = bf16(X[(b*512+s)*1024 + d])
__global__ __launch_bounds__(256) void conv_x(const float* __restrict__ X,
                                              __hip_bfloat16* __restrict__ Xt) {
    size_t id = (size_t)blockIdx.x * 256 + threadIdx.x;   // < 64*512*1024
    int d   = (int)(id & 1023);
    int row = (int)(id >> 10);
    int s = row >> 6;
    int b = row & 63;
    Xt[id] = __float2bfloat16(X[(((size_t)b * 512 + s) << 10) + d]);
}

// h[b*1024+k] = bf16(hx[k]) broadcast; zero the epoch flags (reset every launch).
__global__ __launch_bounds__(256) void init_h(const float* __restrict__ hx,
                                              __hip_bfloat16* __restrict__ h,
                                              unsigned int* __restrict__ cflag,
                                              unsigned int* __restrict__ hflag) {
    int id = blockIdx.x * 256 + threadIdx.x;              // < 65536
    h[id] = __float2bfloat16(hx[id & 1023]);
    if (id < 4096) cflag[id] = 0u;                        // 256 flags x 16 u32 pad
    else if (id < 5120) hflag[id - 4096] = 0u;            // 64 flags x 16 u32 pad
}

// ---------- coherence-point primitives ----------
// 16B IF-coherent load: plain dwordx4 with sc0 sc1 (same semantics as a relaxed
// agent atomic load, but full width). Caller must vm_wait0() before consuming.
__device__ __forceinline__ i32x4 ld_cp16(const void* p) {
    i32x4 r;
    asm volatile("global_load_dwordx4 %0, %1, off sc0 sc1"
                 : "=&v"(r) : "v"(p) : "memory");
    return r;
}
// drain all outstanding VMEM, then fence the scheduler (rule #18)
__device__ __forceinline__ void vm_wait0() {
    asm volatile("s_waitcnt vmcnt(0)" ::: "memory");
    __builtin_amdgcn_sched_barrier(0);
}
// 8B write EXECUTED AT the IF coherence point: returning agent-scope exchange.
// vmcnt clears only when the old value returns from IF (round-5 lesson).
__device__ __forceinline__ void xchg8f(float* p, float lo, float hi) {
    union { float f[2]; unsigned long long u; } c;
    c.f[0] = lo; c.f[1] = hi;
    unsigned long long old =
        __hip_atomic_exchange((unsigned long long*)p, c.u, AT_RLX, SC_AGT);
    asm volatile("" :: "v"(old));
}
__device__ __forceinline__ void xchg8u(unsigned long long* p, unsigned long long v) {
    unsigned long long old = __hip_atomic_exchange(p, v, AT_RLX, SC_AGT);
    asm volatile("" :: "v"(old));
}

// ---------- fused persistent recurrence: flag-pipelined (r6 structure) ----------
// 256 WGs x 256 thr (1 WG/CU). WG b: nt=b>>1 (col tile), mt=b&1 (row block).
// cflag[wg] = s+1 after wg's comb(s) tile is AT the coherence point.
// hflag[r]  = s+1 after row-WG r's h(s) is AT the coherence point.
// Flags 64B-padded, per-lane polls (r6 layout — r7/r8 alternatives measured worse).
// This round: all cross-WG DATA reads are 16B sc0sc1 dwordx4 (batched issue + one
// vmcnt(0) drain) instead of 8B atomic loads -> ~2x fewer IF transactions.
__global__ __launch_bounds__(256, 1) void lstm_fused(
    const __hip_bfloat16* __restrict__ Xt,
    const __hip_bfloat16* __restrict__ Wt,
    __hip_bfloat16* __restrict__ h,
    const float* __restrict__ bias,
    const float* __restrict__ lnw,
    const float* __restrict__ lnb,
    const float* __restrict__ cx,
    float* __restrict__ comb,
    float* __restrict__ out,
    unsigned int* __restrict__ cflag,
    unsigned int* __restrict__ hflag)
{
    const int tid  = threadIdx.x;
    const int lane = tid & 63;
    const int wv   = tid >> 6;          // wave in WG: 0..3
    const int b    = blockIdx.x;        // 0..255

    const int nt = b >> 1;              // col tile 0..127
    const int mt = b & 1;               // row block 0..1
    const int kc = wv;                  // K chunk 0..3  (512 each)
    const int cl = lane & 31;
    const int kh = (lane >> 5) * 8;
    const int n0 = nt * 32;

    __shared__ float lds_f[4096];       // 4 x 32 x 32 split-K partials
    __shared__ float red[8];

    // ---- load this wave's B chunk into registers, once ----
    const short* bp = (const short*)Wt + (size_t)(n0 + cl) * 2048 + kc * 512 + kh;
    bf16x8 breg[32];
#pragma unroll
    for (int i = 0; i < 32; ++i) breg[i] = *(const bf16x8*)(bp + i * 16);

    // ---- A pointers ----
    const short* xbase = (const short*)Xt + (size_t)(mt * 32 + cl) * 1024 + kc * 512 + kh; // + s*65536
    const short* hrow  = (const short*)h  + (size_t)(mt * 32 + cl) * 1024 + (kc - 2) * 512 + kh; // kc>=2
    const unsigned int* myhf = &hflag[(mt * 32 + cl) * 16];   // h-row flag this lane needs
    const unsigned int* mycf = &cflag[(2 * (tid & 127) + (b >> 5)) * 16]; // consumer poll target

    // ---- pointwise persistent state + parameter preloads (rows owned by WGs 0..63) ----
    // thread t owns 4 CONSECUTIVE outputs o = 4t..4t+3 (quad), so comb reads are
    // 16B/gate, h handoff is ONE 8B xchg, out store is one dwordx4.
    float cr[4];
    f32x4 bias_r[4], lnw_r[4], lnb_r[4];
    if (b < 64) {
#pragma unroll
        for (int e = 0; e < 4; ++e) cr[e] = cx[4 * tid + e];
#pragma unroll
        for (int g = 0; g < 4; ++g) {
            bias_r[g] = *(const f32x4*)&bias[1024 * g + 4 * tid];
            lnw_r[g]  = *(const f32x4*)&lnw[1024 * g + 4 * tid];
            lnb_r[g]  = *(const f32x4*)&lnb[1024 * g + 4 * tid];
        }
    }

    for (int s = 0; s < 512; ++s) {
        // ================= phase 1: GEMM, split-K reduced in LDS =================
        f32x16 accA, accB;
#pragma unroll
        for (int i = 0; i < 16; ++i) { accA[i] = 0.f; accB[i] = 0.f; }
        if (kc < 2) {
            const short* ap = xbase + (size_t)s * 65536;
#pragma unroll
            for (int i = 0; i < 16; ++i) {
                bf16x8 a0 = *(const bf16x8*)(ap + i * 16);
                bf16x8 a1 = *(const bf16x8*)(ap + (i + 16) * 16);
                accA = __builtin_amdgcn_mfma_f32_32x32x16_bf16(a0, breg[i],      accA, 0, 0, 0);
                accB = __builtin_amdgcn_mfma_f32_32x32x16_bf16(a1, breg[i + 16], accB, 0, 0, 0);
            }
        } else {
            // wait for h(s-1): per-lane poll of the one row flag this lane reads
            while (__hip_atomic_load(myhf, AT_RLX, SC_AGT) < (unsigned int)s)
                __builtin_amdgcn_s_sleep(1);
            asm volatile("" ::: "memory");
            // batched 16B IF-coherent loads of this lane's h row (32 x dwordx4),
            // single drain, then MFMAs (sched_barrier keeps them after the wait)
            bf16x8 ha[32];
#pragma unroll
            for (int i = 0; i < 32; ++i)
                ha[i] = __builtin_bit_cast(bf16x8, ld_cp16(hrow + i * 16));
            vm_wait0();
#pragma unroll
            for (int i = 0; i < 16; ++i) {
                accA = __builtin_amdgcn_mfma_f32_32x32x16_bf16(ha[i],      breg[i],      accA, 0, 0, 0);
                accB = __builtin_amdgcn_mfma_f32_32x32x16_bf16(ha[i + 16], breg[i + 16], accB, 0, 0, 0);
            }
        }
#pragma unroll
        for (int r = 0; r < 16; ++r) {
            int rl = (r & 3) + 8 * (r >> 2) + 4 * (lane >> 5);
            lds_f[kc * 1024 + rl * 32 + cl] = accA[r] + accB[r];
        }
        __syncthreads();
        {
            float* crow = comb + (size_t)(mt * 32) * 4096 + n0;
#pragma unroll
            for (int half = 0; half < 2; ++half) {
                int e = 2 * tid + half * 512;           // even -> 8B aligned pair
                float2 p0 = *(const float2*)&lds_f[e];
                float2 p1 = *(const float2*)&lds_f[1024 + e];
                float2 p2 = *(const float2*)&lds_f[2048 + e];
                float2 p3 = *(const float2*)&lds_f[3072 + e];
                xchg8f(&crow[(size_t)(e >> 5) * 4096 + (e & 31)],
                       p0.x + p1.x + p2.x + p3.x,
                       p0.y + p1.y + p2.y + p3.y);
            }
        }
        __syncthreads();   // vmcnt(0): exchanges returned from IF -> data globally visible
        if (tid == 0)
            __hip_atomic_store(&cflag[b * 16], (unsigned int)(s + 1), AT_RLX, SC_AGT);

        // ================= phase 2: pointwise (rows on WGs 0..63) =================
        if (b < 64) {
            if (tid < 128) {   // one thread per producer WG of this row-block
                while (__hip_atomic_load(mycf, AT_RLX, SC_AGT) < (unsigned int)(s + 1))
                    __builtin_amdgcn_s_sleep(1);
            }
            __syncthreads();
            asm volatile("" ::: "memory");
            const float* c0 = comb + (size_t)b * 4096;
            // 4 x 16B IF-coherent loads: gate g values for outputs 4t..4t+3
            f32x4 xv[4];
#pragma unroll
            for (int g = 0; g < 4; ++g)
                xv[g] = __builtin_bit_cast(f32x4, ld_cp16(&c0[1024 * g + 4 * tid]));
            vm_wait0();
            float v[4][4];
            float s1 = 0.f, s2 = 0.f;
#pragma unroll
            for (int g = 0; g < 4; ++g)
#pragma unroll
                for (int e = 0; e < 4; ++e) {
                    float x = xv[g][e] + bias_r[g][e];
                    v[g][e] = x;
                    s1 += x;
                    s2 += x * x;
                }
            for (int off = 32; off; off >>= 1) {
                s1 += __shfl_down(s1, off);
                s2 += __shfl_down(s2, off);
            }
            if (lane == 0) { red[2 * wv] = s1; red[2 * wv + 1] = s2; }
            __syncthreads();
            float sum = red[0] + red[2] + red[4] + red[6];
            float ssq = red[1] + red[3] + red[5] + red[7];
            float mean = sum * (1.f / 4096.f);
            float var  = ssq * (1.f / 4096.f) - mean * mean;
            float rstd = rsqrtf(var + 1e-5f);
            float hn[4];
#pragma unroll
            for (int e = 0; e < 4; ++e) {
                float yi = (v[0][e] - mean) * rstd * lnw_r[0][e] + lnb_r[0][e];
                float yf = (v[1][e] - mean) * rstd * lnw_r[1][e] + lnb_r[1][e];
                float yo = (v[2][e] - mean) * rstd * lnw_r[2][e] + lnb_r[2][e];
                float yh = (v[3][e] - mean) * rstd * lnw_r[3][e] + lnb_r[3][e];
                float ig = 1.f / (1.f + __expf(-yi));
                float fg = 1.f / (1.f + __expf(-yf));
                float og = 1.f / (1.f + __expf(-yo));
                float hd = tanhf(yh);
                float cn = fg * cr[e] + ig * hd;
                cr[e] = cn;
                hn[e] = og * tanhf(cn);
            }
            // h handoff FIRST (one 8B xchg: outputs 4t..4t+3), then flag, then out
            unsigned long long hp = 0;
#pragma unroll
            for (int e = 0; e < 4; ++e)
                hp |= (unsigned long long)
                      __builtin_bit_cast(unsigned short, __float2bfloat16(hn[e])) << (16 * e);
            xchg8u((unsigned long long*)((unsigned short*)h + b * 1024 + 4 * tid), hp);
            __syncthreads();   // vmcnt(0): h(s) at coherence point
            if (tid == 0)
                __hip_atomic_store(&hflag[b * 16], (unsigned int)(s + 1), AT_RLX, SC_AGT);
            f32x4 o4;
#pragma unroll
            for (int e = 0; e < 4; ++e) o4[e] = hn[e];
            *(f32x4*)(out + (size_t)b * 524288 + (size_t)s * 1024 + 4 * tid) = o4;
        }
    }
}

// ---------- launcher ----------
extern "C" void kernel_launch(void* const* d_in, const int* in_sizes, int n_in,
                              void* d_out, int out_size, void* d_ws, size_t ws_size,
                              hipStream_t stream) {
    const float* X   = (const float*)d_in[0];   // [64,512,1024]
    const float* W   = (const float*)d_in[1];   // [2048,4096]
    const float* bv  = (const float*)d_in[2];   // [4096]
    const float* lnw = (const float*)d_in[3];   // [4096]
    const float* lnb = (const float*)d_in[4];   // [4096]
    const float* hx  = (const float*)d_in[5];   // [1,1024]
    const float* cx  = (const float*)d_in[6];   // [1,1024]
    float* out = (float*)d_out;                 // [64,512,1024]

    char* base = (char*)d_ws;
    __hip_bfloat16* Wt    = (__hip_bfloat16*)(base);                 // 16 MB
    __hip_bfloat16* Xt    = (__hip_bfloat16*)(base + 16777216);      // 64 MB
    float*          comb  = (float*)         (base + 83886080);      // 1 MB
    __hip_bfloat16* hbuf  = (__hip_bfloat16*)(base + 84934656);      // 128 KB
    unsigned int*   cflag = (unsigned int*)  (base + 85065728);      // 16 KB (256 x 64B)
    unsigned int*   hflag = (unsigned int*)  (base + 85082112);      // 4 KB  (64 x 64B)
    // total ~85.09 MB

    conv_w<<<32768, 256, 0, stream>>>(W, Wt);
    conv_x<<<131072, 256, 0, stream>>>(X, Xt);
    init_h<<<256, 256, 0, stream>>>(hx, hbuf, cflag, hflag);

    lstm_fused<<<256, 256, 0, stream>>>(Xt, Wt, hbuf, bv, lnw, lnb, cx, comb, out,
                                        cflag, hflag);
}